// Round 2
// baseline (170.378 us; speedup 1.0000x reference)
//
#include <hip/hip_runtime.h>

// Problem constants: B,H,W,C = 16,256,256,16 ; HO,WO = 256,256
#define BB 16
#define HH 256
#define WW 256
#define CC 16
#define NPIX (HH * WW)          // 65536 pixels per batch
#define POOL_BLOCKS (BB * 64)   // 1024

typedef float vfloat4 __attribute__((ext_vector_type(4)));

// ---------------------------------------------------------------------------
// Fused stage 1+2: mean-pool partials via shuffle reduce + device atomics;
// the LAST block to finish computes the 16x6 affine params.
// Grid = 1024 blocks (one per batch slice of 16384 floats), 256 threads.
// ws layout (floats): [0..255] sums[b][c], [256] counter (int), [264..359] params
// sums+counter must be zeroed before launch (hipMemsetAsync in kernel_launch).
// ---------------------------------------------------------------------------
__global__ __launch_bounds__(256) void pool_params(
    const float4* __restrict__ x4,
    const float* __restrict__ W_loc,
    const float* __restrict__ b_loc,
    float* __restrict__ sums,      // [16*16]
    int* __restrict__ counter,
    float* __restrict__ params)    // [16*6]
{
    const int blk = blockIdx.x;            // b*64 + slice
    const int tid = threadIdx.x;
    const int b   = blk >> 6;

    // Slice = 4096 float4; thread reads 16 float4 at stride 256 (coalesced).
    const float4* p = x4 + (size_t)blk * 4096 + tid;
    float4 acc = {0.f, 0.f, 0.f, 0.f};
#pragma unroll
    for (int k = 0; k < 16; ++k) {
        float4 v = p[k * 256];
        acc.x += v.x; acc.y += v.y; acc.z += v.z; acc.w += v.w;
    }
    // Wave reduce: lanes with equal (lane&3) share a channel quad.
    for (int off = 4; off < 64; off <<= 1) {
        acc.x += __shfl_down(acc.x, off);
        acc.y += __shfl_down(acc.y, off);
        acc.z += __shfl_down(acc.z, off);
        acc.w += __shfl_down(acc.w, off);
    }
    __shared__ float4 wsum[4][4];
    const int wave = tid >> 6, lane = tid & 63;
    if (lane < 4) wsum[wave][lane] = acc;
    __syncthreads();
    if (tid < 4) {
        float4 t0 = wsum[0][tid], t1 = wsum[1][tid];
        float4 t2 = wsum[2][tid], t3 = wsum[3][tid];
        float4 t;
        t.x = t0.x + t1.x + t2.x + t3.x;
        t.y = t0.y + t1.y + t2.y + t3.y;
        t.z = t0.z + t1.z + t2.z + t3.z;
        t.w = t0.w + t1.w + t2.w + t3.w;
        atomicAdd(&sums[b * 16 + tid * 4 + 0], t.x);
        atomicAdd(&sums[b * 16 + tid * 4 + 1], t.y);
        atomicAdd(&sums[b * 16 + tid * 4 + 2], t.z);
        atomicAdd(&sums[b * 16 + tid * 4 + 3], t.w);
    }
    __syncthreads();                       // adders done before counter bump
    __shared__ int isLast;
    if (tid == 0) {
        __threadfence();
        int prev = atomicAdd(counter, 1);
        isLast = (prev == POOL_BLOCKS - 1) ? 1 : 0;
    }
    __syncthreads();
    if (isLast) {
        __shared__ float pooled[BB][CC];
        const int b2 = tid >> 4, c2 = tid & 15;
        // atomic read-back guarantees device-coherent view of the sums
        float v = atomicAdd(&sums[b2 * 16 + c2], 0.0f);
        pooled[b2][c2] = v * (1.0f / 65536.0f);
        __syncthreads();
        if (tid < BB * 6) {
            const int bb = tid / 6, j = tid % 6;
            float a = b_loc[j];
#pragma unroll
            for (int c = 0; c < CC; ++c)
                a += pooled[bb][c] * W_loc[c * 6 + j];
            params[bb * 6 + j] = a;
        }
    }
}

// ---------------------------------------------------------------------------
// Stage 3: bilinear sampling. 4 threads per output pixel (one float4 channel
// quad each). b is derived from blockIdx only -> params loads scalarize.
// Grid = 16 * 1024 blocks, 256 threads (64 pixels/block, one row segment).
// ---------------------------------------------------------------------------
__global__ __launch_bounds__(256) void sample(
    const float4* __restrict__ x4,
    const float* __restrict__ params,
    float4* __restrict__ out)
{
    const int tid = threadIdx.x;
    const int b   = blockIdx.x >> 10;                       // wave-uniform
    const int pix = ((blockIdx.x & 1023) << 6) + (tid >> 2);
    const int cq  = tid & 3;
    const int h   = pix >> 8;
    const int w   = pix & 255;

    const float* pr = params + b * 6;
    const float p0 = pr[0], p1 = pr[1], p2 = pr[2];
    const float p3 = pr[3], p4 = pr[4], p5 = pr[5];

    const float fh = (float)h, fw = (float)w;
    const float yc = p0 * fh + p1 * fw + p4;
    const float xc = p2 * fh + p3 * fw + p5;

    const float y0f = floorf(yc), x0f = floorf(xc);
    const float wy = yc - y0f, wx = xc - x0f;
    const int y0 = (int)y0f, x0 = (int)x0f;
    const int y0i = min(max(y0, 0), HH - 1);
    const int y1i = min(max(y0 + 1, 0), HH - 1);
    const int x0i = min(max(x0, 0), WW - 1);
    const int x1i = min(max(x0 + 1, 0), WW - 1);

    const size_t base = (size_t)b * NPIX;
    const float4* r0 = x4 + (base + (size_t)y0i * WW) * 4 + cq;
    const float4* r1 = x4 + (base + (size_t)y1i * WW) * 4 + cq;
    const float4 Ia = r0[(size_t)x0i * 4];
    const float4 Ib = r0[(size_t)x1i * 4];
    const float4 Ic = r1[(size_t)x0i * 4];
    const float4 Id = r1[(size_t)x1i * 4];

    const float wa = (1.f - wy) * (1.f - wx);
    const float wb = (1.f - wy) * wx;
    const float wc = wy * (1.f - wx);
    const float wd = wy * wx;

    vfloat4 o;
    o.x = wa * Ia.x + wb * Ib.x + wc * Ic.x + wd * Id.x;
    o.y = wa * Ia.y + wb * Ib.y + wc * Ic.y + wd * Id.y;
    o.z = wa * Ia.z + wb * Ib.z + wc * Ic.z + wd * Id.z;
    o.w = wa * Ia.w + wb * Ib.w + wc * Ic.w + wd * Id.w;

    // Streaming 67 MB write: bypass L2 so x stays resident for the gather.
    __builtin_nontemporal_store(o, (vfloat4*)&out[(base + pix) * 4 + cq]);
}

extern "C" void kernel_launch(void* const* d_in, const int* in_sizes, int n_in,
                              void* d_out, int out_size, void* d_ws, size_t ws_size,
                              hipStream_t stream) {
    const float* x     = (const float*)d_in[0];   // (16,256,256,16) f32
    const float* W_loc = (const float*)d_in[1];   // (16,6) f32
    const float* b_loc = (const float*)d_in[2];   // (6,) f32
    // d_in[3] = coords_grid == np.indices((256,256)) -> recomputed on-chip.

    float* wsf    = (float*)d_ws;
    float* sums   = wsf;                // 256 floats
    int*   counter= (int*)(wsf + 256);  // 1 int
    float* params = wsf + 264;          // 96 floats

    // Zero sums + counter (ws is poisoned 0xAA before every timed call).
    hipMemsetAsync(d_ws, 0, 257 * sizeof(float), stream);

    pool_params<<<POOL_BLOCKS, 256, 0, stream>>>(
        (const float4*)x, W_loc, b_loc, sums, counter, params);

    sample<<<BB * 1024, 256, 0, stream>>>(
        (const float4*)x, params, (float4*)d_out);
}

// Round 3
// 140.780 us; speedup vs baseline: 1.2102x; 1.2102x over previous
//
#include <hip/hip_runtime.h>

// Problem constants: B,H,W,C = 16,256,256,16 ; HO,WO = 256,256
#define BB 16
#define HH 256
#define WW 256
#define CC 16
#define NPIX (HH * WW)            // 65536 pixels per batch
#define SLICES 128                // slices per batch for pooling
#define POOL_BLOCKS (BB * SLICES) // 2048 blocks

// ---------------------------------------------------------------------------
// Stage 1: partial mean-pool. 2048 blocks (8/CU -> full occupancy), 256 thr.
// Each block = one batch slice of 8192 contiguous floats (2048 float4);
// thread reads 8 float4 at stride 256 (coalesced). Deterministic, no atomics.
// Output: part[blk*4 + g] (float4) = partial sums of channels 4g..4g+3.
// ---------------------------------------------------------------------------
__global__ __launch_bounds__(256) void pool_partial(const float4* __restrict__ x4,
                                                    float4* __restrict__ part) {
    const int blk = blockIdx.x;          // b*128 + slice
    const int tid = threadIdx.x;
    const float4* p = x4 + (size_t)blk * 2048 + tid;
    float4 acc = {0.f, 0.f, 0.f, 0.f};
#pragma unroll
    for (int k = 0; k < 8; ++k) {
        float4 v = p[k * 256];
        acc.x += v.x; acc.y += v.y; acc.z += v.z; acc.w += v.w;
    }
    // Wave shuffle-reduce: lanes with equal (lane&3) share a channel quad.
    for (int off = 4; off < 64; off <<= 1) {
        acc.x += __shfl_down(acc.x, off);
        acc.y += __shfl_down(acc.y, off);
        acc.z += __shfl_down(acc.z, off);
        acc.w += __shfl_down(acc.w, off);
    }
    __shared__ float4 wsum[4][4];
    const int wave = tid >> 6, lane = tid & 63;
    if (lane < 4) wsum[wave][lane] = acc;
    __syncthreads();
    if (tid < 4) {
        float4 t0 = wsum[0][tid], t1 = wsum[1][tid];
        float4 t2 = wsum[2][tid], t3 = wsum[3][tid];
        float4 t;
        t.x = t0.x + t1.x + t2.x + t3.x;
        t.y = t0.y + t1.y + t2.y + t3.y;
        t.z = t0.z + t1.z + t2.z + t3.z;
        t.w = t0.w + t1.w + t2.w + t3.w;
        part[blk * 4 + tid] = t;
    }
}

// ---------------------------------------------------------------------------
// Stage 2: finish pooling + 16x6 matmul. One block, 256 threads.
// part float layout: [blk][16 ch], blk = b*128+s. Thread (b,c) sums 128
// values at stride 16 floats (coalesced within each 16-thread group).
// ---------------------------------------------------------------------------
__global__ __launch_bounds__(256) void compute_params(const float* __restrict__ part,
                                                      const float* __restrict__ W_loc,
                                                      const float* __restrict__ b_loc,
                                                      float* __restrict__ params) {
    __shared__ float pooled[BB][CC];
    const int tid = threadIdx.x;          // 256 = B*C
    const int b = tid >> 4;
    const int c = tid & 15;
    const float* q = part + (size_t)b * SLICES * CC + c;
    float s = 0.f;
#pragma unroll 8
    for (int k = 0; k < SLICES; ++k)
        s += q[k * CC];
    pooled[b][c] = s * (1.0f / 65536.0f);
    __syncthreads();
    if (tid < BB * 6) {
        const int bb = tid / 6, j = tid % 6;
        float a = b_loc[j];
#pragma unroll
        for (int cc = 0; cc < CC; ++cc)
            a += pooled[bb][cc] * W_loc[cc * 6 + j];
        params[bb * 6 + j] = a;
    }
}

// ---------------------------------------------------------------------------
// Stage 3: bilinear sampling. 4 threads per output pixel (one float4 channel
// quad each). b derived from blockIdx only -> params loads scalarize.
// Grid = 16 * 1024 blocks, 256 threads (64 pixels/block = 1/4 output row).
// ---------------------------------------------------------------------------
__global__ __launch_bounds__(256) void sample(
    const float4* __restrict__ x4,
    const float* __restrict__ params,
    float4* __restrict__ out)
{
    const int tid = threadIdx.x;
    const int b   = blockIdx.x >> 10;                       // wave-uniform
    const int pix = ((blockIdx.x & 1023) << 6) + (tid >> 2);
    const int cq  = tid & 3;
    const int h   = pix >> 8;
    const int w   = pix & 255;

    const float* pr = params + b * 6;
    const float p0 = pr[0], p1 = pr[1], p2 = pr[2];
    const float p3 = pr[3], p4 = pr[4], p5 = pr[5];

    const float fh = (float)h, fw = (float)w;
    const float yc = p0 * fh + p1 * fw + p4;
    const float xc = p2 * fh + p3 * fw + p5;

    const float y0f = floorf(yc), x0f = floorf(xc);
    const float wy = yc - y0f, wx = xc - x0f;
    const int y0 = (int)y0f, x0 = (int)x0f;
    const int y0i = min(max(y0, 0), HH - 1);
    const int y1i = min(max(y0 + 1, 0), HH - 1);
    const int x0i = min(max(x0, 0), WW - 1);
    const int x1i = min(max(x0 + 1, 0), WW - 1);

    const size_t base = (size_t)b * NPIX;
    const float4* r0 = x4 + (base + (size_t)y0i * WW) * 4 + cq;
    const float4* r1 = x4 + (base + (size_t)y1i * WW) * 4 + cq;
    const float4 Ia = r0[(size_t)x0i * 4];
    const float4 Ib = r0[(size_t)x1i * 4];
    const float4 Ic = r1[(size_t)x0i * 4];
    const float4 Id = r1[(size_t)x1i * 4];

    const float wa = (1.f - wy) * (1.f - wx);
    const float wb = (1.f - wy) * wx;
    const float wc = wy * (1.f - wx);
    const float wd = wy * wx;

    float4 o;
    o.x = wa * Ia.x + wb * Ib.x + wc * Ic.x + wd * Id.x;
    o.y = wa * Ia.y + wb * Ib.y + wc * Ic.y + wd * Id.y;
    o.z = wa * Ia.z + wb * Ib.z + wc * Ic.z + wd * Id.z;
    o.w = wa * Ia.w + wb * Ib.w + wc * Ic.w + wd * Id.w;

    out[(base + pix) * 4 + cq] = o;
}

extern "C" void kernel_launch(void* const* d_in, const int* in_sizes, int n_in,
                              void* d_out, int out_size, void* d_ws, size_t ws_size,
                              hipStream_t stream) {
    const float* x     = (const float*)d_in[0];   // (16,256,256,16) f32
    const float* W_loc = (const float*)d_in[1];   // (16,6) f32
    const float* b_loc = (const float*)d_in[2];   // (6,) f32
    // d_in[3] = coords_grid == np.indices((256,256)) -> recomputed on-chip.

    float* part   = (float*)d_ws;                 // 2048*16 floats (fully written)
    float* params = part + POOL_BLOCKS * CC;      // 96 floats (fully written)

    pool_partial<<<POOL_BLOCKS, 256, 0, stream>>>((const float4*)x, (float4*)part);
    compute_params<<<1, 256, 0, stream>>>(part, W_loc, b_loc, params);
    sample<<<BB * 1024, 256, 0, stream>>>((const float4*)x, params, (float4*)d_out);
}

// Round 5
// 131.188 us; speedup vs baseline: 1.2987x; 1.0731x over previous
//
#include <hip/hip_runtime.h>

// Problem constants: B,H,W,C = 16,256,256,16 ; HO,WO = 256,256
#define BB 16
#define HH 256
#define WW 256
#define CC 16
#define NPIX (HH * WW)            // 65536 pixels per batch
#define SLICES 128                // pool slices per batch
#define POOL_BLOCKS (BB * SLICES) // 2048 blocks

// ---------------------------------------------------------------------------
// Kernel 1: partial mean-pool. 2048 blocks (8/CU), 256 threads.
// Block = one batch slice of 8192 contiguous floats (2048 float4);
// thread reads 8 float4 at stride 256 (coalesced). Deterministic.
// Output: part[blk*4 + g] (float4) = partial sums of channels 4g..4g+3,
// blk = b*128 + s  ->  batch b owns part[b*512 .. b*512+512) float4s.
// ---------------------------------------------------------------------------
__global__ __launch_bounds__(256) void pool_partial(const float4* __restrict__ x4,
                                                    float4* __restrict__ part) {
    const int blk = blockIdx.x;
    const int tid = threadIdx.x;
    const float4* p = x4 + (size_t)blk * 2048 + tid;
    float4 acc = {0.f, 0.f, 0.f, 0.f};
#pragma unroll
    for (int k = 0; k < 8; ++k) {
        float4 v = p[k * 256];
        acc.x += v.x; acc.y += v.y; acc.z += v.z; acc.w += v.w;
    }
    // Lanes with equal (lane&3) share a channel quad.
    for (int off = 4; off < 64; off <<= 1) {
        acc.x += __shfl_down(acc.x, off);
        acc.y += __shfl_down(acc.y, off);
        acc.z += __shfl_down(acc.z, off);
        acc.w += __shfl_down(acc.w, off);
    }
    __shared__ float4 wsum[4][4];
    const int wave = tid >> 6, lane = tid & 63;
    if (lane < 4) wsum[wave][lane] = acc;
    __syncthreads();
    if (tid < 4) {
        float4 t0 = wsum[0][tid], t1 = wsum[1][tid];
        float4 t2 = wsum[2][tid], t3 = wsum[3][tid];
        float4 t;
        t.x = t0.x + t1.x + t2.x + t3.x;
        t.y = t0.y + t1.y + t2.y + t3.y;
        t.z = t0.z + t1.z + t2.z + t3.z;
        t.w = t0.w + t1.w + t2.w + t3.w;
        part[blk * 4 + tid] = t;
    }
}

// ---------------------------------------------------------------------------
// Kernel 2: per-block params prologue (4 KB L2-hit reduce + 16x6 matmul),
// then bilinear sampling. Grid = 1024 blocks (64/batch), 256 threads.
// Each block covers 1024 pixels (4 output rows); 4 lanes per pixel, one
// float4 channel quad each; 16 pixel-quads per thread.
// ---------------------------------------------------------------------------
__global__ __launch_bounds__(256) void sample_fused(
    const float4* __restrict__ x4,
    const float* __restrict__ W_loc,
    const float* __restrict__ b_loc,
    const float4* __restrict__ part,
    float4* __restrict__ out)
{
    const int tid  = threadIdx.x;
    const int blk  = blockIdx.x;          // b*64 + local
    const int b    = blk >> 6;
    const int wave = tid >> 6, lane = tid & 63;

    __shared__ float4 wsum[4][4];
    __shared__ float  pooled[CC];
    __shared__ float  pr[6];

    // ---- params prologue: reduce this batch's 512 float4 partials ----
    {
        const float4* q = part + (size_t)b * 512;
        float4 a0 = q[tid], a1 = q[tid + 256];
        float4 acc;
        acc.x = a0.x + a1.x; acc.y = a0.y + a1.y;
        acc.z = a0.z + a1.z; acc.w = a0.w + a1.w;
        for (int off = 4; off < 64; off <<= 1) {
            acc.x += __shfl_down(acc.x, off);
            acc.y += __shfl_down(acc.y, off);
            acc.z += __shfl_down(acc.z, off);
            acc.w += __shfl_down(acc.w, off);
        }
        if (lane < 4) wsum[wave][lane] = acc;
        __syncthreads();
        if (tid < 4) {
            float4 t0 = wsum[0][tid], t1 = wsum[1][tid];
            float4 t2 = wsum[2][tid], t3 = wsum[3][tid];
            pooled[tid * 4 + 0] = (t0.x + t1.x + t2.x + t3.x) * (1.0f / 65536.0f);
            pooled[tid * 4 + 1] = (t0.y + t1.y + t2.y + t3.y) * (1.0f / 65536.0f);
            pooled[tid * 4 + 2] = (t0.z + t1.z + t2.z + t3.z) * (1.0f / 65536.0f);
            pooled[tid * 4 + 3] = (t0.w + t1.w + t2.w + t3.w) * (1.0f / 65536.0f);
        }
        __syncthreads();
        if (tid < 6) {
            float a = b_loc[tid];
#pragma unroll
            for (int c = 0; c < CC; ++c)
                a += pooled[c] * W_loc[c * 6 + tid];
            pr[tid] = a;
        }
        __syncthreads();
    }

    // ---- bilinear sampling ----
    const float p0 = pr[0], p1 = pr[1], p2 = pr[2];
    const float p3 = pr[3], p4 = pr[4], p5 = pr[5];
    const size_t base    = (size_t)b * NPIX;
    const int    pixBase = (blk & 63) * 1024 + (tid >> 2);
    const int    cq      = tid & 3;

#pragma unroll 4
    for (int k = 0; k < 16; ++k) {
        const int pix = pixBase + k * 64;
        const int h = pix >> 8;
        const int w = pix & 255;

        const float fh = (float)h, fw = (float)w;
        const float yc = p0 * fh + p1 * fw + p4;
        const float xc = p2 * fh + p3 * fw + p5;

        const float y0f = floorf(yc), x0f = floorf(xc);
        const float wy = yc - y0f, wx = xc - x0f;
        const int y0 = (int)y0f, x0 = (int)x0f;
        const int y0i = min(max(y0, 0), HH - 1);
        const int y1i = min(max(y0 + 1, 0), HH - 1);
        const int x0i = min(max(x0, 0), WW - 1);
        const int x1i = min(max(x0 + 1, 0), WW - 1);

        const float4* r0 = x4 + (base + (size_t)y0i * WW) * 4 + cq;
        const float4* r1 = x4 + (base + (size_t)y1i * WW) * 4 + cq;
        const float4 Ia = r0[(size_t)x0i * 4];
        const float4 Ib = r0[(size_t)x1i * 4];
        const float4 Ic = r1[(size_t)x0i * 4];
        const float4 Id = r1[(size_t)x1i * 4];

        const float wa = (1.f - wy) * (1.f - wx);
        const float wb = (1.f - wy) * wx;
        const float wc = wy * (1.f - wx);
        const float wd = wy * wx;

        float4 o;
        o.x = wa * Ia.x + wb * Ib.x + wc * Ic.x + wd * Id.x;
        o.y = wa * Ia.y + wb * Ib.y + wc * Ic.y + wd * Id.y;
        o.z = wa * Ia.z + wb * Ib.z + wc * Ic.z + wd * Id.z;
        o.w = wa * Ia.w + wb * Ib.w + wc * Ic.w + wd * Id.w;

        out[(base + pix) * 4 + cq] = o;
    }
}

extern "C" void kernel_launch(void* const* d_in, const int* in_sizes, int n_in,
                              void* d_out, int out_size, void* d_ws, size_t ws_size,
                              hipStream_t stream) {
    const float* x     = (const float*)d_in[0];   // (16,256,256,16) f32
    const float* W_loc = (const float*)d_in[1];   // (16,6) f32
    const float* b_loc = (const float*)d_in[2];   // (6,) f32
    // d_in[3] = coords_grid == np.indices((256,256)) -> recomputed on-chip.

    float4* part = (float4*)d_ws;                 // 2048*4 float4, fully written

    pool_partial<<<POOL_BLOCKS, 256, 0, stream>>>((const float4*)x, part);
    sample_fused<<<BB * 64, 256, 0, stream>>>((const float4*)x, W_loc, b_loc,
                                              part, (float4*)d_out);
}

// Round 6
// 129.901 us; speedup vs baseline: 1.3116x; 1.0099x over previous
//
#include <hip/hip_runtime.h>

// Problem constants: B,H,W,C = 16,256,256,16 ; HO,WO = 256,256
#define BB 16
#define HH 256
#define WW 256
#define CC 16
#define NPIX (HH * WW)            // 65536 pixels per batch
#define SLICES 128                // pool slices per batch
#define POOL_BLOCKS (BB * SLICES) // 2048 blocks
#define SAMPLE_BPB 128            // sample blocks per batch
#define SAMPLE_BLOCKS (BB * SAMPLE_BPB) // 2048 blocks

// ---------------------------------------------------------------------------
// Kernel 1: partial mean-pool. 2048 blocks, 256 threads.
// Block = one batch slice of 8192 contiguous floats (2048 float4);
// thread reads 8 float4 at stride 256 (coalesced). Deterministic.
// Output: part[blk*4 + g] (float4) = partial sums of channels 4g..4g+3,
// blk = b*128 + s  ->  batch b owns part[b*512 .. b*512+512) float4s.
// ---------------------------------------------------------------------------
__global__ __launch_bounds__(256) void pool_partial(const float4* __restrict__ x4,
                                                    float4* __restrict__ part) {
    const int blk = blockIdx.x;
    const int tid = threadIdx.x;
    const float4* p = x4 + (size_t)blk * 2048 + tid;
    float4 acc = {0.f, 0.f, 0.f, 0.f};
#pragma unroll
    for (int k = 0; k < 8; ++k) {
        float4 v = p[k * 256];
        acc.x += v.x; acc.y += v.y; acc.z += v.z; acc.w += v.w;
    }
    // Lanes with equal (lane&3) share a channel quad.
    for (int off = 4; off < 64; off <<= 1) {
        acc.x += __shfl_down(acc.x, off);
        acc.y += __shfl_down(acc.y, off);
        acc.z += __shfl_down(acc.z, off);
        acc.w += __shfl_down(acc.w, off);
    }
    __shared__ float4 wsum[4][4];
    const int wave = tid >> 6, lane = tid & 63;
    if (lane < 4) wsum[wave][lane] = acc;
    __syncthreads();
    if (tid < 4) {
        float4 t0 = wsum[0][tid], t1 = wsum[1][tid];
        float4 t2 = wsum[2][tid], t3 = wsum[3][tid];
        float4 t;
        t.x = t0.x + t1.x + t2.x + t3.x;
        t.y = t0.y + t1.y + t2.y + t3.y;
        t.z = t0.z + t1.z + t2.z + t3.z;
        t.w = t0.w + t1.w + t2.w + t3.w;
        part[blk * 4 + tid] = t;
    }
}

// ---------------------------------------------------------------------------
// Kernel 2: per-block params prologue (4 KB L2 reduce + 16x6 matmul), then
// bilinear sampling. Grid = 2048 blocks (128/batch -> 8 blocks/CU for full
// occupancy), 256 threads. Block covers 512 pixels (2 output rows); 4 lanes
// per pixel, one float4 channel quad each; 8 pixel-quads per thread.
// ---------------------------------------------------------------------------
__global__ __launch_bounds__(256) void sample_fused(
    const float4* __restrict__ x4,
    const float* __restrict__ W_loc,
    const float* __restrict__ b_loc,
    const float4* __restrict__ part,
    float4* __restrict__ out)
{
    const int tid  = threadIdx.x;
    const int blk  = blockIdx.x;          // b*128 + local
    const int b    = blk >> 7;
    const int wave = tid >> 6, lane = tid & 63;

    __shared__ float4 wsum[4][4];
    __shared__ float  pooled[CC];
    __shared__ float  pr[6];

    // ---- params prologue: reduce this batch's 512 float4 partials ----
    {
        const float4* q = part + (size_t)b * 512;
        float4 a0 = q[tid], a1 = q[tid + 256];
        float4 acc;
        acc.x = a0.x + a1.x; acc.y = a0.y + a1.y;
        acc.z = a0.z + a1.z; acc.w = a0.w + a1.w;
        for (int off = 4; off < 64; off <<= 1) {
            acc.x += __shfl_down(acc.x, off);
            acc.y += __shfl_down(acc.y, off);
            acc.z += __shfl_down(acc.z, off);
            acc.w += __shfl_down(acc.w, off);
        }
        if (lane < 4) wsum[wave][lane] = acc;
        __syncthreads();
        if (tid < 4) {
            float4 t0 = wsum[0][tid], t1 = wsum[1][tid];
            float4 t2 = wsum[2][tid], t3 = wsum[3][tid];
            pooled[tid * 4 + 0] = (t0.x + t1.x + t2.x + t3.x) * (1.0f / 65536.0f);
            pooled[tid * 4 + 1] = (t0.y + t1.y + t2.y + t3.y) * (1.0f / 65536.0f);
            pooled[tid * 4 + 2] = (t0.z + t1.z + t2.z + t3.z) * (1.0f / 65536.0f);
            pooled[tid * 4 + 3] = (t0.w + t1.w + t2.w + t3.w) * (1.0f / 65536.0f);
        }
        __syncthreads();
        if (tid < 6) {
            float a = b_loc[tid];
#pragma unroll
            for (int c = 0; c < CC; ++c)
                a += pooled[c] * W_loc[c * 6 + tid];
            pr[tid] = a;
        }
        __syncthreads();
    }

    // ---- bilinear sampling: 8 pixel-quads per thread ----
    const float p0 = pr[0], p1 = pr[1], p2 = pr[2];
    const float p3 = pr[3], p4 = pr[4], p5 = pr[5];
    const size_t base    = (size_t)b * NPIX;
    const int    pixBase = (blk & 127) * 512 + (tid >> 2);
    const int    cq      = tid & 3;

#pragma unroll 4
    for (int k = 0; k < 8; ++k) {
        const int pix = pixBase + k * 64;
        const int h = pix >> 8;
        const int w = pix & 255;

        const float fh = (float)h, fw = (float)w;
        const float yc = p0 * fh + p1 * fw + p4;
        const float xc = p2 * fh + p3 * fw + p5;

        const float y0f = floorf(yc), x0f = floorf(xc);
        const float wy = yc - y0f, wx = xc - x0f;
        const int y0 = (int)y0f, x0 = (int)x0f;
        const int y0i = min(max(y0, 0), HH - 1);
        const int y1i = min(max(y0 + 1, 0), HH - 1);
        const int x0i = min(max(x0, 0), WW - 1);
        const int x1i = min(max(x0 + 1, 0), WW - 1);

        const float4* r0 = x4 + (base + (size_t)y0i * WW) * 4 + cq;
        const float4* r1 = x4 + (base + (size_t)y1i * WW) * 4 + cq;
        const float4 Ia = r0[(size_t)x0i * 4];
        const float4 Ib = r0[(size_t)x1i * 4];
        const float4 Ic = r1[(size_t)x0i * 4];
        const float4 Id = r1[(size_t)x1i * 4];

        const float wa = (1.f - wy) * (1.f - wx);
        const float wb = (1.f - wy) * wx;
        const float wc = wy * (1.f - wx);
        const float wd = wy * wx;

        float4 o;
        o.x = wa * Ia.x + wb * Ib.x + wc * Ic.x + wd * Id.x;
        o.y = wa * Ia.y + wb * Ib.y + wc * Ic.y + wd * Id.y;
        o.z = wa * Ia.z + wb * Ib.z + wc * Ic.z + wd * Id.z;
        o.w = wa * Ia.w + wb * Ib.w + wc * Ic.w + wd * Id.w;

        out[(base + pix) * 4 + cq] = o;
    }
}

extern "C" void kernel_launch(void* const* d_in, const int* in_sizes, int n_in,
                              void* d_out, int out_size, void* d_ws, size_t ws_size,
                              hipStream_t stream) {
    const float* x     = (const float*)d_in[0];   // (16,256,256,16) f32
    const float* W_loc = (const float*)d_in[1];   // (16,6) f32
    const float* b_loc = (const float*)d_in[2];   // (6,) f32
    // d_in[3] = coords_grid == np.indices((256,256)) -> recomputed on-chip.

    float4* part = (float4*)d_ws;                 // 2048*4 float4, fully written

    pool_partial<<<POOL_BLOCKS, 256, 0, stream>>>((const float4*)x, part);
    sample_fused<<<SAMPLE_BLOCKS, 256, 0, stream>>>((const float4*)x, W_loc, b_loc,
                                                    part, (float4*)d_out);
}